// Round 18
// baseline (4341.769 us; speedup 1.0000x reference)
//
#include <hip/hip_runtime.h>

typedef _Float16 half_t;
typedef _Float16 half8 __attribute__((ext_vector_type(8)));
typedef float f32x4 __attribute__((ext_vector_type(4)));
typedef unsigned long long u64;
typedef unsigned int u32;
typedef unsigned short u16;

#define GROUPS 16
#define WPG 8
#define CPS 4              // chains (groups) per WG-set
#define NWG 32             // 4 sets x 8 WGs
#define THREADS 512
#define TSTEPS 512

// ws layout
#define W0_HALVES (8*8*10*64*8)    // 327680 halves
#define W1_HALVES (8*8*16*64*8)    // 524288 halves
#define X_HALVES  (512*16*1024)    // 8388608 halves
#define HX_U32    (2*GROUPS*4096)  // per layer: 2 slots x 16 groups x 4096 stamped u32

#define LDS_TOTAL (CPS*2*16384)    // 4 chains x 2 slots x 16KB = 131072 B

__device__ __forceinline__ float sigm(float x){ return 1.f/(1.f+__expf(-x)); }
__device__ __forceinline__ float tanh_fast(float x){ float e=__expf(2.f*x); return 1.f - 2.f/(e+1.f); }

// W0 blocks: [jw 0..63][kc 0..9][lane][8]; wave jw owns h [jw*4, jw*4+4)
__global__ void prep_w0(const float* __restrict__ Wih, const float* __restrict__ Whh,
                        half_t* __restrict__ dst){
  int idx = blockIdx.x*blockDim.x + threadIdx.x;
  if (idx >= 8*8*10*64) return;
  int lane = idx & 63;
  int kc = (idx >> 6) % 10;
  int jw = idx / 640;
  int tr = lane & 15, kg = lane >> 4;
  int grow = (tr&3)*256 + jw*4 + (tr>>2);
  int k0 = kc*32 + kg*8;
  half_t* d = dst + (size_t)idx*8;
#pragma unroll
  for (int jj=0;jj<8;jj++){
    int k = k0 + jj;
    float v = (k < 64) ? Wih[grow*64 + k] : Whh[grow*256 + (k - 64)];
    d[jj] = (half_t)v;
  }
}

// W1 blocks: [jw][kc 0..15][lane][8]; K = [h0(256) | h1(256)]
__global__ void prep_w1(const float* __restrict__ Wih, const float* __restrict__ Whh,
                        half_t* __restrict__ dst){
  int idx = blockIdx.x*blockDim.x + threadIdx.x;
  if (idx >= 8*8*16*64) return;
  int lane = idx & 63;
  int kc = (idx >> 6) & 15;
  int jw = idx >> 10;
  int tr = lane & 15, kg = lane >> 4;
  int grow = (tr&3)*256 + jw*4 + (tr>>2);
  int k0 = kc*32 + kg*8;
  half_t* d = dst + (size_t)idx*8;
#pragma unroll
  for (int jj=0;jj<8;jj++){
    int k = k0 + jj;
    float v = (k < 256) ? Wih[grow*256 + k] : Whh[grow*256 + (k - 256)];
    d[jj] = (half_t)v;
  }
}

// x -> [t][g 0..15][k8 0..7][b 0..15][8] fp16
__global__ void prep_x(const float* __restrict__ x, half_t* __restrict__ xblk){
  int idx = blockIdx.x*blockDim.x + threadIdx.x;
  if (idx >= 512*16*8*16) return;
  int b = idx & 15;
  int k8 = (idx >> 4) & 7;
  int g = (idx >> 7) & 15;
  int t = idx >> 11;
  const float* src = x + ((size_t)(g*16+b)*512 + (size_t)t)*64 + k8*8;
  half_t* d = xblk + (size_t)idx*8;
#pragma unroll
  for (int jj=0;jj<8;jj++) d[jj] = (half_t)src[jj];
}

// r15's proven stamped poll+stage: coalesced u64 loads (poll IS the fetch),
// scatter packed fp16 into LDS fragment layout.
// exchange wave-major: e = jw*64 + lane; decode m: jw=m>>5, kg=(m>>3)&3, lc0=(2m)&15.
__device__ __forceinline__ void poll_stage(const u64* s, half_t* sb, int tid, u32 want){
  u64 v[4];
  int ok = 0;
  for (int tries = 0; !ok && tries < (1<<20); ++tries){
    ok = 1;
#pragma unroll
    for (int i = 0; i < 4; ++i)
      v[i] = __hip_atomic_load(s + tid + i*512, __ATOMIC_RELAXED, __HIP_MEMORY_SCOPE_AGENT);
#pragma unroll
    for (int i = 0; i < 4; ++i)
      ok &= (int)((((u32)(v[i] >> 16) & 0xFFFFu) >= want) & (((u32)(v[i] >> 48)) >= want));
  }
#pragma unroll
  for (int i = 0; i < 4; ++i){
    int m = tid + i*512;
    int jw2 = m >> 5, kg2 = (m >> 3) & 3, lc0 = (2*m) & 15;
    int hh2 = jw2*4 + kg2;
    half_t* d = sb + ((hh2 >> 3)*16 + lc0)*8 + (hh2 & 7);
    d[0] = __builtin_bit_cast(half_t, (u16)(v[i] & 0xFFFFu));
    d[8] = __builtin_bit_cast(half_t, (u16)((v[i] >> 32) & 0xFFFFu));
  }
}

// persistent distributed 2-layer LSTM, 4-way chain-multiplexed:
// 4 sets x 8 WGs; WG owns 32 h for 4 independent batch-chains (groups st*4+ch).
// Per phase: poll all 4 chains (only the first pays the LLC visibility latency),
// one barrier, then 4x (L0+L1 compute + stamped coalesced stores).
__global__ __launch_bounds__(THREADS, 1) void lstm_dist(
    const half_t* __restrict__ W0blk, const half_t* __restrict__ W1blk,
    const half_t* __restrict__ xblk,
    u32* __restrict__ h0x, u32* __restrict__ h1x,
    const float* __restrict__ b_ih0, const float* __restrict__ b_hh0,
    const float* __restrict__ b_ih1, const float* __restrict__ b_hh1,
    const float* __restrict__ W_head, const float* __restrict__ b_head,
    float* __restrict__ out)
{
  extern __shared__ __align__(16) char smem[];
  half_t* hb = (half_t*)smem;   // [ch][slot][h0:4096|h1:4096] halves

  const int tid = threadIdx.x;
  const int wave = tid >> 6, lane = tid & 63;
  const int lcol = lane & 15, kg = lane >> 4;
  const int bid = blockIdx.x;
  const int st = bid >> 3, j = bid & 7;
  const int jw = j*8 + wave;

  // ---- one-time: A-fragments + biases into registers (shared by all 4 chains) ----
  half8 a0[10], a1[16];
#pragma unroll
  for (int kc = 0; kc < 10; ++kc)
    a0[kc] = *(const half8*)(W0blk + ((size_t)(jw*10 + kc)*64 + lane)*8);
#pragma unroll
  for (int kc = 0; kc < 16; ++kc)
    a1[kc] = *(const half8*)(W1blk + ((size_t)(jw*16 + kc)*64 + lane)*8);
#pragma unroll
  for (int kc = 0; kc < 10; ++kc) asm volatile("" : "+v"(a0[kc]));
#pragma unroll
  for (int kc = 0; kc < 16; ++kc) asm volatile("" : "+v"(a1[kc]));

  const int hh = jw*4 + kg;                 // lane's hidden index (0..255)
  const int eoff = jw*64 + lane;            // wave-major exchange u32 index
  f32x4 bias0, bias1;
#pragma unroll
  for (int ri = 0; ri < 4; ++ri){
    bias0[ri] = b_ih0[ri*256+hh] + b_hh0[ri*256+hh];
    bias1[ri] = b_ih1[ri*256+hh] + b_hh1[ri*256+hh];
  }

  // zero all chain buffers (h0(-1)=h1(-1)=h1(-2)=0 for every chain)
  for (int i = tid; i < LDS_TOTAL/4; i += THREADS) ((u32*)hb)[i] = 0u;

  float c0[CPS], c1[CPS];
#pragma unroll
  for (int ch = 0; ch < CPS; ++ch){ c0[ch] = 0.f; c1[ch] = 0.f; }

  half8 xf[CPS][2];
#pragma unroll
  for (int ch = 0; ch < CPS; ++ch){
    const half_t* xs = xblk + (size_t)(st*CPS + ch)*1024;
    xf[ch][0] = *(const half8*)(xs + ((0*4+kg)*16 + lcol)*8);
    xf[ch][1] = *(const half8*)(xs + ((1*4+kg)*16 + lcol)*8);
  }
  __syncthreads();

  for (int q = 0; q <= TSTEPS; ++q){
    const int sslot = (q+1)&1, dslot = q&1;
    const u32 want = (u32)q;

    // ---- A) poll+stage ALL chains (chain 0 pays vis; 1..3 are already ready) ----
    if (q > 0){
#pragma unroll
      for (int ch = 0; ch < CPS; ++ch){
        const int g = st*CPS + ch;
        half_t* sb = hb + (size_t)(ch*2 + sslot)*8192;
        poll_stage((const u64*)(h0x + (size_t)(sslot*GROUPS + g)*4096), sb, tid, want);
        if (q > 1)
          poll_stage((const u64*)(h1x + (size_t)(sslot*GROUPS + g)*4096), sb + 4096, tid, want);
      }
    }
    __syncthreads();   // staged data visible; single barrier per phase

    // ---- B) compute + store, chain by chain ----
#pragma unroll
    for (int ch = 0; ch < CPS; ++ch){
      const int g = st*CPS + ch;
      const half_t* cb = hb + (size_t)(ch*2 + sslot)*8192;
      half8 h0f[8];
#pragma unroll
      for (int c = 0; c < 8; ++c)
        h0f[c] = *(const half8*)(cb + ((c*4+kg)*16 + lcol)*8);

      if (q < TSTEPS){
        __builtin_amdgcn_s_setprio(1);
        f32x4 acc = bias0;
        acc = __builtin_amdgcn_mfma_f32_16x16x32_f16(a0[0], xf[ch][0], acc, 0,0,0);
        acc = __builtin_amdgcn_mfma_f32_16x16x32_f16(a0[1], xf[ch][1], acc, 0,0,0);
#pragma unroll
        for (int c = 0; c < 8; ++c)
          acc = __builtin_amdgcn_mfma_f32_16x16x32_f16(a0[c+2], h0f[c], acc, 0,0,0);
        float ig=sigm(acc[0]), fg=sigm(acc[1]), gg=tanh_fast(acc[2]), og=sigm(acc[3]);
        c0[ch] = fg*c0[ch] + ig*gg;
        float hv = og*tanh_fast(c0[ch]);
        u32 sv = ((u32)(q+1) << 16) | (u32)__builtin_bit_cast(u16, (half_t)hv);
        __hip_atomic_store(h0x + (size_t)(dslot*GROUPS + g)*4096 + eoff, sv,
                           __ATOMIC_RELAXED, __HIP_MEMORY_SCOPE_AGENT);
        __builtin_amdgcn_s_setprio(0);
        __builtin_amdgcn_sched_barrier(0);   // issue the store before moving on
      }

      if (q >= 1){
        __builtin_amdgcn_s_setprio(1);
        f32x4 acc = bias1;
#pragma unroll
        for (int c = 0; c < 8; ++c)
          acc = __builtin_amdgcn_mfma_f32_16x16x32_f16(a1[c], h0f[c], acc, 0,0,0);
#pragma unroll
        for (int c = 0; c < 8; ++c){
          half8 h1f = *(const half8*)(cb + 4096 + ((c*4+kg)*16 + lcol)*8);
          acc = __builtin_amdgcn_mfma_f32_16x16x32_f16(a1[c+8], h1f, acc, 0,0,0);
        }
        float ig=sigm(acc[0]), fg=sigm(acc[1]), gg=tanh_fast(acc[2]), og=sigm(acc[3]);
        c1[ch] = fg*c1[ch] + ig*gg;
        float hv = og*tanh_fast(c1[ch]);
        u32 sv = ((u32)(q+1) << 16) | (u32)__builtin_bit_cast(u16, (half_t)hv);
        __hip_atomic_store(h1x + (size_t)(dslot*GROUPS + g)*4096 + eoff, sv,
                           __ATOMIC_RELAXED, __HIP_MEMORY_SCOPE_AGENT);
        __builtin_amdgcn_s_setprio(0);
        __builtin_amdgcn_sched_barrier(0);
      }
    }

    // ---- C) x prefetch for next phase (overlaps next poll) ----
    if (q+1 < TSTEPS){
#pragma unroll
      for (int ch = 0; ch < CPS; ++ch){
        const half_t* xs = xblk + (size_t)((q+1)*16 + st*CPS + ch)*1024;
        xf[ch][0] = *(const half8*)(xs + ((0*4+kg)*16 + lcol)*8);
        xf[ch][1] = *(const half8*)(xs + ((1*4+kg)*16 + lcol)*8);
      }
    }
  }

  __syncthreads();

  // ---- head: poll final h1(511) (slot 0, stamp 513) per chain, stage, GEMV ----
  {
#pragma unroll
    for (int ch = 0; ch < CPS; ++ch){
      const int g = st*CPS + ch;
      poll_stage((const u64*)(h1x + (size_t)(0*GROUPS + g)*4096),
                 hb + (size_t)(ch*2)*8192, tid, (u32)(TSTEPS + 1));
    }
    __syncthreads();

    if (tid < 240){
      int bl = 2*j + (tid >= 120 ? 1 : 0);
      int o = tid % 120;
      const float* wr = W_head + (size_t)o*256;
      float bh = b_head[o];
#pragma unroll
      for (int ch = 0; ch < CPS; ++ch){
        const int g = st*CPS + ch;
        const half_t* hbch = hb + (size_t)(ch*2)*8192;
        float s2 = bh;
#pragma unroll 4
        for (int k8 = 0; k8 < 32; ++k8){
          half8 hv = *(const half8*)(hbch + (k8*16 + bl)*8);
#pragma unroll
          for (int jj = 0; jj < 8; ++jj)
            s2 += (float)hv[jj] * wr[k8*8 + jj];
        }
        out[((size_t)(g*16 + bl))*120 + o] = s2;
      }
    }
  }
}

extern "C" void kernel_launch(void* const* d_in, const int* in_sizes, int n_in,
                              void* d_out, int out_size, void* d_ws, size_t ws_size,
                              hipStream_t stream){
  const float* x     = (const float*)d_in[0];
  const float* W_ih0 = (const float*)d_in[1];
  const float* W_hh0 = (const float*)d_in[2];
  const float* b_ih0 = (const float*)d_in[3];
  const float* b_hh0 = (const float*)d_in[4];
  const float* W_ih1 = (const float*)d_in[5];
  const float* W_hh1 = (const float*)d_in[6];
  const float* b_ih1 = (const float*)d_in[7];
  const float* b_hh1 = (const float*)d_in[8];
  const float* W_head= (const float*)d_in[9];
  const float* b_head= (const float*)d_in[10];
  float* out = (float*)d_out;

  half_t* W0blk = (half_t*)d_ws;
  half_t* W1blk = W0blk + W0_HALVES;
  half_t* xblk  = W1blk + W1_HALVES;
  u32*    h0x   = (u32*)(xblk + X_HALVES);
  u32*    h1x   = h0x + HX_U32;

  // zero stamped exchange buffers every launch (graph-replay safe)
  (void)hipMemsetAsync(h0x, 0, (size_t)HX_U32*2*4, stream);   // h0x + h1x contiguous

  hipLaunchKernelGGL(prep_w0, dim3(160), dim3(256), 0, stream, W_ih0, W_hh0, W0blk);
  hipLaunchKernelGGL(prep_w1, dim3(256), dim3(256), 0, stream, W_ih1, W_hh1, W1blk);
  hipLaunchKernelGGL(prep_x,  dim3(4096), dim3(256), 0, stream, x, xblk);

  (void)hipFuncSetAttribute((const void*)lstm_dist,
                            hipFuncAttributeMaxDynamicSharedMemorySize, LDS_TOTAL);

  hipLaunchKernelGGL(lstm_dist, dim3(NWG), dim3(THREADS), LDS_TOTAL, stream,
                     W0blk, W1blk, xblk, h0x, h1x,
                     b_ih0, b_hh0, b_ih1, b_hh1, W_head, b_head, out);
}

// Round 19
// 1419.340 us; speedup vs baseline: 3.0590x; 3.0590x over previous
//
#include <hip/hip_runtime.h>

typedef _Float16 half_t;
typedef _Float16 half8 __attribute__((ext_vector_type(8)));
typedef float f32x4 __attribute__((ext_vector_type(4)));
typedef unsigned long long u64;
typedef unsigned int u32;
typedef unsigned short u16;

#define GROUPS 16
#define WPG 8
#define NWG 128
#define THREADS 512
#define TSTEPS 512

// ws layout
#define W0_HALVES (8*8*10*64*8)    // 327680 halves
#define W1_HALVES (8*8*16*64*8)    // 524288 halves
#define X_HALVES  (512*16*1024)    // 8388608 halves
#define HX_U32    (2*GROUPS*4096)  // per layer: 2 slots x 16 groups x 4096 stamped u32

__device__ __forceinline__ float sigm(float x){ return 1.f/(1.f+__expf(-x)); }
__device__ __forceinline__ float tanh_fast(float x){ float e=__expf(2.f*x); return 1.f - 2.f/(e+1.f); }

// W0 blocks: [jw 0..63][kc 0..9][lane][8]; wave jw owns h [jw*4, jw*4+4)
__global__ void prep_w0(const float* __restrict__ Wih, const float* __restrict__ Whh,
                        half_t* __restrict__ dst){
  int idx = blockIdx.x*blockDim.x + threadIdx.x;
  if (idx >= 8*8*10*64) return;
  int lane = idx & 63;
  int kc = (idx >> 6) % 10;
  int jw = idx / 640;
  int tr = lane & 15, kg = lane >> 4;
  int grow = (tr&3)*256 + jw*4 + (tr>>2);
  int k0 = kc*32 + kg*8;
  half_t* d = dst + (size_t)idx*8;
#pragma unroll
  for (int jj=0;jj<8;jj++){
    int k = k0 + jj;
    float v = (k < 64) ? Wih[grow*64 + k] : Whh[grow*256 + (k - 64)];
    d[jj] = (half_t)v;
  }
}

// W1 blocks: [jw][kc 0..15][lane][8]; K = [h0(256) | h1(256)]
__global__ void prep_w1(const float* __restrict__ Wih, const float* __restrict__ Whh,
                        half_t* __restrict__ dst){
  int idx = blockIdx.x*blockDim.x + threadIdx.x;
  if (idx >= 8*8*16*64) return;
  int lane = idx & 63;
  int kc = (idx >> 6) & 15;
  int jw = idx >> 10;
  int tr = lane & 15, kg = lane >> 4;
  int grow = (tr&3)*256 + jw*4 + (tr>>2);
  int k0 = kc*32 + kg*8;
  half_t* d = dst + (size_t)idx*8;
#pragma unroll
  for (int jj=0;jj<8;jj++){
    int k = k0 + jj;
    float v = (k < 256) ? Wih[grow*256 + k] : Whh[grow*256 + (k - 256)];
    d[jj] = (half_t)v;
  }
}

// x -> [t][g 0..15][k8 0..7][b 0..15][8] fp16
__global__ void prep_x(const float* __restrict__ x, half_t* __restrict__ xblk){
  int idx = blockIdx.x*blockDim.x + threadIdx.x;
  if (idx >= 512*16*8*16) return;
  int b = idx & 15;
  int k8 = (idx >> 4) & 7;
  int g = (idx >> 7) & 15;
  int t = idx >> 11;
  const float* src = x + ((size_t)(g*16+b)*512 + (size_t)t)*64 + k8*8;
  half_t* d = xblk + (size_t)idx*8;
#pragma unroll
  for (int jj=0;jj<8;jj++) d[jj] = (half_t)src[jj];
}

// stamped-poll a 16 KB layer slice (2048 u64 / 512 threads = 4 u64/thread) and
// scatter packed fp16 into LDS fragment layout.
// exchange layout is WAVE-MAJOR: e = jw*64 + lane  -> producer stores fully coalesced.
// decode of u64 index m (covers e=2m,2m+1): jw=m>>5, kg=(m>>3)&3, lcol=(2m)&15.
__device__ __forceinline__ void poll_stage(const u64* s, half_t* sb, int tid, u32 want){
  u64 v[4];
  int ok = 0;
  for (int tries = 0; !ok && tries < (1<<20); ++tries){
    ok = 1;
#pragma unroll
    for (int i = 0; i < 4; ++i)
      v[i] = __hip_atomic_load(s + tid + i*512, __ATOMIC_RELAXED, __HIP_MEMORY_SCOPE_AGENT);
#pragma unroll
    for (int i = 0; i < 4; ++i)
      ok &= (int)((((u32)(v[i] >> 16) & 0xFFFFu) >= want) & (((u32)(v[i] >> 48)) >= want));
  }
#pragma unroll
  for (int i = 0; i < 4; ++i){
    int m = tid + i*512;
    int jw2 = m >> 5, kg2 = (m >> 3) & 3, lc0 = (2*m) & 15;
    int hh2 = jw2*4 + kg2;
    half_t* d = sb + ((hh2 >> 3)*16 + lc0)*8 + (hh2 & 7);
    d[0] = __builtin_bit_cast(half_t, (u16)(v[i] & 0xFFFFu));
    d[8] = __builtin_bit_cast(half_t, (u16)((v[i] >> 32) & 0xFFFFu));
  }
}

// persistent distributed 2-layer LSTM: 16 groups x 8 WGs; WG owns 32 h x 16 batch
// exchange: per-value stamped u32 ((step+1)<<16 | fp16), wave-major coalesced stores
__global__ __launch_bounds__(THREADS, 1) void lstm_dist(
    const half_t* __restrict__ W0blk, const half_t* __restrict__ W1blk,
    const half_t* __restrict__ xblk,
    u32* __restrict__ h0x, u32* __restrict__ h1x,
    const float* __restrict__ b_ih0, const float* __restrict__ b_hh0,
    const float* __restrict__ b_ih1, const float* __restrict__ b_hh1,
    const float* __restrict__ W_head, const float* __restrict__ b_head,
    float* __restrict__ out)
{
  __shared__ __align__(16) half_t hbuf[2][8192];  // [slot][h0:4096 | h1:4096] halves

  const int tid = threadIdx.x;
  const int wave = tid >> 6, lane = tid & 63;
  const int lcol = lane & 15, kg = lane >> 4;
  const int bid = blockIdx.x;
  const int g = bid >> 3, j = bid & 7;
  const int jw = j*8 + wave;

  // ---- one-time: A-fragments + biases into registers ----
  half8 a0[10], a1[16];
#pragma unroll
  for (int kc = 0; kc < 10; ++kc)
    a0[kc] = *(const half8*)(W0blk + ((size_t)(jw*10 + kc)*64 + lane)*8);
#pragma unroll
  for (int kc = 0; kc < 16; ++kc)
    a1[kc] = *(const half8*)(W1blk + ((size_t)(jw*16 + kc)*64 + lane)*8);
#pragma unroll
  for (int kc = 0; kc < 10; ++kc) asm volatile("" : "+v"(a0[kc]));
#pragma unroll
  for (int kc = 0; kc < 16; ++kc) asm volatile("" : "+v"(a1[kc]));

  const int hh = jw*4 + kg;                 // lane's hidden index (0..255)
  const int eoff = jw*64 + lane;            // WAVE-MAJOR exchange u32 index
  f32x4 bias0, bias1;
#pragma unroll
  for (int ri = 0; ri < 4; ++ri){
    bias0[ri] = b_ih0[ri*256+hh] + b_hh0[ri*256+hh];
    bias1[ri] = b_ih1[ri*256+hh] + b_hh1[ri*256+hh];
  }

  // zero both LDS slots (serves as h0(-1)=h1(-1)=h1(-2)=0)
  for (int i = tid; i < 8192; i += THREADS) ((u32*)hbuf)[i] = 0u;

  float c0 = 0.f, c1 = 0.f;
  half8 xf0, xf1;
  {
    const half_t* xs = xblk + (size_t)g*1024;
    xf0 = *(const half8*)(xs + ((0*4+kg)*16 + lcol)*8);
    xf1 = *(const half8*)(xs + ((1*4+kg)*16 + lcol)*8);
  }
  __syncthreads();

  for (int q = 0; q <= TSTEPS; ++q){
    const int sslot = (q+1)&1, dslot = q&1;
    const u32 want = (u32)q;

    // ---- A) poll+stage h0(q-1) (poll IS the fetch; scatter to fragment LDS) ----
    if (q > 0)
      poll_stage((const u64*)(h0x + (size_t)(sslot*GROUPS + g)*4096),
                 hbuf[sslot], tid, want);
    __syncthreads();   // staged h0 visible; drains last phase's L1 stores (slot-reuse safe)

    const half_t* cb = hbuf[sslot];
    half8 h0f[8];
#pragma unroll
    for (int c = 0; c < 8; ++c)
      h0f[c] = *(const half8*)(cb + ((c*4+kg)*16 + lcol)*8);

    // ---- B) L0: step q (high prio: issue the coalesced h0 store ASAP) ----
    if (q < TSTEPS){
      __builtin_amdgcn_s_setprio(1);
      f32x4 acc = bias0;
      acc = __builtin_amdgcn_mfma_f32_16x16x32_f16(a0[0], xf0, acc, 0,0,0);
      acc = __builtin_amdgcn_mfma_f32_16x16x32_f16(a0[1], xf1, acc, 0,0,0);
#pragma unroll
      for (int c = 0; c < 8; ++c)
        acc = __builtin_amdgcn_mfma_f32_16x16x32_f16(a0[c+2], h0f[c], acc, 0,0,0);
      float ig=sigm(acc[0]), fg=sigm(acc[1]), gg=tanh_fast(acc[2]), og=sigm(acc[3]);
      c0 = fg*c0 + ig*gg;
      float hv = og*tanh_fast(c0);
      u32 sv = ((u32)(q+1) << 16) | (u32)__builtin_bit_cast(u16, (half_t)hv);
      __hip_atomic_store(h0x + (size_t)(dslot*GROUPS + g)*4096 + eoff, sv,
                         __ATOMIC_RELAXED, __HIP_MEMORY_SCOPE_AGENT);
      __builtin_amdgcn_s_setprio(0);
      __builtin_amdgcn_sched_barrier(0);   // issue the store before the h1 poll
    }

    // ---- C) poll+stage h1(q-2): overlaps producers' L1 of phase q-1 ----
    if (q > 1)
      poll_stage((const u64*)(h1x + (size_t)(sslot*GROUPS + g)*4096),
                 hbuf[sslot] + 4096, tid, want);
    __syncthreads();   // drains this phase's L0 store too (overlapped with the poll)

    // ---- D) L1: step q-1 (high prio) ----
    if (q >= 1){
      __builtin_amdgcn_s_setprio(1);
      f32x4 acc = bias1;
#pragma unroll
      for (int c = 0; c < 8; ++c)
        acc = __builtin_amdgcn_mfma_f32_16x16x32_f16(a1[c], h0f[c], acc, 0,0,0);
#pragma unroll
      for (int c = 0; c < 8; ++c){
        half8 h1f = *(const half8*)(cb + 4096 + ((c*4+kg)*16 + lcol)*8);
        acc = __builtin_amdgcn_mfma_f32_16x16x32_f16(a1[c+8], h1f, acc, 0,0,0);
      }
      float ig=sigm(acc[0]), fg=sigm(acc[1]), gg=tanh_fast(acc[2]), og=sigm(acc[3]);
      c1 = fg*c1 + ig*gg;
      float hv = og*tanh_fast(c1);
      u32 sv = ((u32)(q+1) << 16) | (u32)__builtin_bit_cast(u16, (half_t)hv);
      __hip_atomic_store(h1x + (size_t)(dslot*GROUPS + g)*4096 + eoff, sv,
                         __ATOMIC_RELAXED, __HIP_MEMORY_SCOPE_AGENT);
      __builtin_amdgcn_s_setprio(0);
    }

    // ---- E) x prefetch for next phase (overlaps next poll) ----
    if (q+1 < TSTEPS){
      const half_t* xs = xblk + (size_t)((q+1)*16 + g)*1024;
      xf0 = *(const half8*)(xs + ((0*4+kg)*16 + lcol)*8);
      xf1 = *(const half8*)(xs + ((1*4+kg)*16 + lcol)*8);
    }
  }

  __syncthreads();

  // ---- head: poll final h1(511) (slot 0, stamp 513), scatter-stage, GEMV ----
  {
    poll_stage((const u64*)(h1x + (size_t)(0*GROUPS + g)*4096),
               hbuf[0], tid, (u32)(TSTEPS + 1));
    __syncthreads();

    if (tid < 240){
      int bl = 2*j + (tid >= 120 ? 1 : 0);
      int o = tid % 120;
      float s2 = b_head[o];
      const float* wr = W_head + (size_t)o*256;
#pragma unroll 4
      for (int k8 = 0; k8 < 32; ++k8){
        half8 hv = *(const half8*)(hbuf[0] + (k8*16 + bl)*8);
#pragma unroll
        for (int jj = 0; jj < 8; ++jj)
          s2 += (float)hv[jj] * wr[k8*8 + jj];
      }
      out[((size_t)(g*16 + bl))*120 + o] = s2;
    }
  }
}

extern "C" void kernel_launch(void* const* d_in, const int* in_sizes, int n_in,
                              void* d_out, int out_size, void* d_ws, size_t ws_size,
                              hipStream_t stream){
  const float* x     = (const float*)d_in[0];
  const float* W_ih0 = (const float*)d_in[1];
  const float* W_hh0 = (const float*)d_in[2];
  const float* b_ih0 = (const float*)d_in[3];
  const float* b_hh0 = (const float*)d_in[4];
  const float* W_ih1 = (const float*)d_in[5];
  const float* W_hh1 = (const float*)d_in[6];
  const float* b_ih1 = (const float*)d_in[7];
  const float* b_hh1 = (const float*)d_in[8];
  const float* W_head= (const float*)d_in[9];
  const float* b_head= (const float*)d_in[10];
  float* out = (float*)d_out;

  half_t* W0blk = (half_t*)d_ws;
  half_t* W1blk = W0blk + W0_HALVES;
  half_t* xblk  = W1blk + W1_HALVES;
  u32*    h0x   = (u32*)(xblk + X_HALVES);
  u32*    h1x   = h0x + HX_U32;

  // zero stamped exchange buffers every launch (graph-replay safe)
  (void)hipMemsetAsync(h0x, 0, (size_t)HX_U32*2*4, stream);   // h0x + h1x contiguous

  hipLaunchKernelGGL(prep_w0, dim3(160), dim3(256), 0, stream, W_ih0, W_hh0, W0blk);
  hipLaunchKernelGGL(prep_w1, dim3(256), dim3(256), 0, stream, W_ih1, W_hh1, W1blk);
  hipLaunchKernelGGL(prep_x,  dim3(4096), dim3(256), 0, stream, x, xblk);

  hipLaunchKernelGGL(lstm_dist, dim3(NWG), dim3(THREADS), 0, stream,
                     W0blk, W1blk, xblk, h0x, h1x,
                     b_ih0, b_hh0, b_ih1, b_hh1, W_head, b_head, out);
}